// Round 7
// baseline (175.156 us; speedup 1.0000x reference)
//
#include <hip/hip_runtime.h>
#include <math.h>
#include <stdint.h>

// Rotated IoU loss, mixed fp64/fp32.
// fp64 spine: corners (poly sincos), intersection num/den (cancellation-critical),
//             shoelace accumulation (fp64 fma of fp32 products).
// fp32: in-box tests, masks (compares of fp64-computed values), vertex coords,
//       masked mean, pseudo-angle keys, iou + log.
// Sort: packed u32 key (27-bit sortable-float pseudo-angle + 5-bit index; stable
//       ties like np.argsort) with fp32 (x,y) payload carried in registers.
// launch_bounds(256,3): the (256,4) cap made the allocator spill ~100B/thread
// to scratch (51MB of WRITE_SIZE, round 6); (256,3) fits spill-free (round 4).

__device__ __forceinline__ float rcp_nr(float x) {
  float r = __builtin_amdgcn_rcpf(x);
  return r * (2.0f - x * r);   // 1 Newton step: ~1 ulp
}

__device__ __forceinline__ void cswapf(bool sw, float& a, float& b) {
  const float t = a; a = sw ? b : a; b = sw ? t : b;
}

// |x| <= ~1.88 guaranteed (pred angle in (-pi/2,pi/2), target += +-0.3).
// Taylor to x^21 / x^22: remainder < 1e-16 relative at |x|=1.88.
__device__ __forceinline__ void sincos_poly(double x, double& s, double& c) {
  const double z = x * x;
  double ps = 1.0 / 51090942171709440000.0;          // 1/21!
  ps = fma(ps, z, -1.0 / 121645100408832000.0);      // -1/19!
  ps = fma(ps, z,  1.0 / 355687428096000.0);
  ps = fma(ps, z, -1.0 / 1307674368000.0);
  ps = fma(ps, z,  1.0 / 6227020800.0);
  ps = fma(ps, z, -1.0 / 39916800.0);
  ps = fma(ps, z,  1.0 / 362880.0);
  ps = fma(ps, z, -1.0 / 5040.0);
  ps = fma(ps, z,  1.0 / 120.0);
  ps = fma(ps, z, -1.0 / 6.0);
  ps = fma(ps, z,  1.0);
  s = x * ps;
  double pc = -1.0 / 1124000727777607680000.0;       // -1/22!
  pc = fma(pc, z,  1.0 / 2432902008176640000.0);     // 1/20!
  pc = fma(pc, z, -1.0 / 6402373705728000.0);
  pc = fma(pc, z,  1.0 / 20922789888000.0);
  pc = fma(pc, z, -1.0 / 87178291200.0);
  pc = fma(pc, z,  1.0 / 479001600.0);
  pc = fma(pc, z, -1.0 / 3628800.0);
  pc = fma(pc, z,  1.0 / 40320.0);
  pc = fma(pc, z, -1.0 / 720.0);
  pc = fma(pc, z,  1.0 / 24.0);
  pc = fma(pc, z, -0.5);
  pc = fma(pc, z,  1.0);
  c = pc;
}

__global__ __launch_bounds__(256, 3) void riou_loss_kernel(
    const float* __restrict__ pred, const float* __restrict__ tgt,
    float* __restrict__ out, int N, float invN)
{
  __shared__ float smem[4];

  const int i = blockIdx.x * 256 + threadIdx.x;
  float loss = 0.0f;
  if (i < N) {
    const float* p = pred + (size_t)i * 5;
    const float* t = tgt + (size_t)i * 5;
    const double px = (double)p[0], py = (double)p[1], pw = (double)p[2],
                 ph = (double)p[3], pa = (double)p[4];
    const double tx = (double)t[0], ty = (double)t[1], tw = (double)t[2],
                 th = (double)t[3], ta = (double)t[4];

    // --- fp64 corners via center +- rotated half-diagonal offsets ---
    // corner order k=0..3: offsets (+,+),(-,+),(-,-),(+,-) scaled by (w/2,h/2):
    // c[2] = center - off0, c[3] = center - off1 (exact reflection symmetry).
    double c1x[4], c1y[4], c2x[4], c2y[4];
    {
      double sa, ca; sincos_poly(pa, sa, ca);
      const double hx = 0.5 * pw, hy = 0.5 * ph;
      const double o0x = hx * ca - hy * sa, o0y = hx * sa + hy * ca;   // (+,+)
      const double o1x = -hx * ca - hy * sa, o1y = -hx * sa + hy * ca; // (-,+)
      c1x[0] = px + o0x; c1y[0] = py + o0y;
      c1x[1] = px + o1x; c1y[1] = py + o1y;
      c1x[2] = px - o0x; c1y[2] = py - o0y;
      c1x[3] = px - o1x; c1y[3] = py - o1y;
    }
    {
      double sa, ca; sincos_poly(ta, sa, ca);
      const double hx = 0.5 * tw, hy = 0.5 * th;
      const double o0x = hx * ca - hy * sa, o0y = hx * sa + hy * ca;
      const double o1x = -hx * ca - hy * sa, o1y = -hx * sa + hy * ca;
      c2x[0] = tx + o0x; c2y[0] = ty + o0y;
      c2x[1] = tx + o1x; c2y[1] = ty + o1y;
      c2x[2] = tx - o0x; c2y[2] = ty - o0y;
      c2x[3] = tx - o1x; c2y[3] = ty - o1y;
    }

    // fp32 vertex bank (static-indexed registers): 0..3 c1, 4..7 c2, 8..23 inters
    float fvx[24], fvy[24];
    #pragma unroll
    for (int k = 0; k < 4; k++) {
      fvx[k] = (float)c1x[k]; fvy[k] = (float)c1y[k];
      fvx[4 + k] = (float)c2x[k]; fvy[4 + k] = (float)c2y[k];
    }

    uint32_t vbit = 0;                       // valid-vertex bitmask
    float sxm = 0.0f, sym = 0.0f, nvf = 0.0f;

    // --- in-box tests (fp32; tolerance 1e-6 >> fp32 test error ~1e-7) ---
    {  // c1 corners inside c2
      const float ax = fvx[4], ay = fvy[4];
      const float abx = fvx[5] - ax, aby = fvy[5] - ay;
      const float adx = fvx[7] - ax, ady = fvy[7] - ay;
      const float idab = rcp_nr(abx * abx + aby * aby);
      const float idad = rcp_nr(adx * adx + ady * ady);
      #pragma unroll
      for (int k = 0; k < 4; k++) {
        const float amx = fvx[k] - ax, amy = fvy[k] - ay;
        const float pab = (abx * amx + aby * amy) * idab;
        const float pad = (adx * amx + ady * amy) * idad;
        const bool in2 = (pab > -1e-6f) && (pab < 1.0f + 1e-6f) &&
                         (pad > -1e-6f) && (pad < 1.0f + 1e-6f);
        vbit |= in2 ? (1u << k) : 0u;
        sxm += in2 ? fvx[k] : 0.0f;
        sym += in2 ? fvy[k] : 0.0f;
        nvf += in2 ? 1.0f : 0.0f;
      }
    }
    {  // c2 corners inside c1
      const float ax = fvx[0], ay = fvy[0];
      const float abx = fvx[1] - ax, aby = fvy[1] - ay;
      const float adx = fvx[3] - ax, ady = fvy[3] - ay;
      const float idab = rcp_nr(abx * abx + aby * aby);
      const float idad = rcp_nr(adx * adx + ady * ady);
      #pragma unroll
      for (int k = 0; k < 4; k++) {
        const float amx = fvx[4 + k] - ax, amy = fvy[4 + k] - ay;
        const float pab = (abx * amx + aby * amy) * idab;
        const float pad = (adx * amx + ady * amy) * idad;
        const bool in1 = (pab > -1e-6f) && (pab < 1.0f + 1e-6f) &&
                         (pad > -1e-6f) && (pad < 1.0f + 1e-6f);
        vbit |= in1 ? (1u << (4 + k)) : 0u;
        sxm += in1 ? fvx[4 + k] : 0.0f;
        sym += in1 ? fvy[4 + k] : 0.0f;
        nvf += in1 ? 1.0f : 0.0f;
      }
    }

    // --- edge-edge intersections: fp64 num/den, fp32 masks + points ---
    // Edge vectors: e[k+2] = -e[k] exactly (rectangle), so num(a,b) =
    // cross(e2[b], e1[a]) has 4 distinct values up to sign:
    //   num(a,b) = (-1)^((a>>1)+(b>>1)) * nb[a&1][b&1].
    double e1x[2], e1y[2], e2x[2], e2y[2];
    float f1x[4], f1y[4];
    #pragma unroll
    for (int k = 0; k < 2; k++) {
      e1x[k] = c1x[k + 1] - c1x[k]; e1y[k] = c1y[k + 1] - c1y[k];
      e2x[k] = c2x[k + 1] - c2x[k]; e2y[k] = c2y[k + 1] - c2y[k];
      f1x[k] = (float)e1x[k]; f1y[k] = (float)e1y[k];
      f1x[k + 2] = -f1x[k];   f1y[k + 2] = -f1y[k];
    }
    double nb[2][2];
    #pragma unroll
    for (int a = 0; a < 2; a++)
      #pragma unroll
      for (int b = 0; b < 2; b++)
        nb[a][b] = e2y[b] * e1x[a] - e2x[b] * e1y[a];

    #pragma unroll
    for (int a = 0; a < 4; a++) {
      const double ex1 = (a < 2) ? e1x[a & 1] : -e1x[a & 1];
      const double ey1 = (a < 2) ? e1y[a & 1] : -e1y[a & 1];
      #pragma unroll
      for (int b = 0; b < 4; b++) {
        const double ex2 = (b < 2) ? e2x[b & 1] : -e2x[b & 1];
        const double ey2 = (b < 2) ? e2y[b & 1] : -e2y[b & 1];
        const double dx13 = c1x[a] - c2x[b], dy13 = c1y[a] - c2y[b];
        const double num  = (((a >> 1) ^ (b >> 1)) & 1) ? -nb[a & 1][b & 1]
                                                        :  nb[a & 1][b & 1];
        const double dent = ex2 * dy13 - ey2 * dx13;
        const double denu = ex1 * dy13 - ey1 * dx13;
        const float numf = (float)num, dtf = (float)dent, duf = (float)denu;
        // t,u strictly in (0,1): sign tests, no division
        const bool mk = (numf > 0.0f)
            ? ((dtf > 0.0f) && (dtf < numf) && (duf > 0.0f) && (duf < numf))
            : ((numf < 0.0f) && (dtf < 0.0f) && (dtf > numf) && (duf < 0.0f) && (duf > numf));
        // ref quirk: t = den_t / (num + 1e-8)
        const float tt = dtf * rcp_nr(numf + 1e-8f);
        const float ix = fvx[a] + tt * f1x[a];
        const float iy = fvy[a] + tt * f1y[a];
        const int id = 8 + a * 4 + b;
        fvx[id] = ix; fvy[id] = iy;
        vbit |= mk ? (1u << id) : 0u;
        sxm += mk ? ix : 0.0f;
        sym += mk ? iy : 0.0f;
        nvf += mk ? 1.0f : 0.0f;
      }
    }

    // --- masked mean + packed sort keys ---
    const float invn = 1.0f / fmaxf(nvf, 1.0f);
    const float mx = sxm * invn, my = sym * invn;
    uint32_t s[24];
    #pragma unroll
    for (int k = 0; k < 24; k++) {
      const float xf = fvx[k] - mx, yf = fvy[k] - my;
      const float den = fabsf(xf) + fabsf(yf);
      const float pp = (den == 0.0f) ? 1.0f : xf * __builtin_amdgcn_rcpf(den);
      const float ky = (yf >= 0.0f) ? -pp : (pp - 2.0f);  // monotone in atan2 over (-pi,pi]
      const uint32_t u = __float_as_uint(ky);
      const uint32_t srt = u ^ ((u & 0x80000000u) ? 0xFFFFFFFFu : 0x80000000u);
      const bool valid = (vbit >> k) & 1u;
      // 27-bit key + 5-bit index (stable ties, like np.argsort); invalid -> max class
      s[k] = valid ? ((srt & 0xFFFFFFE0u) | (uint32_t)k) : (0xFFFFFFE0u | (uint32_t)k);
    }

    // --- Batcher odd-even mergesort, n=32 pruned to 24 wires, payload in regs ---
    #pragma unroll
    for (int pp2 = 1; pp2 < 32; pp2 <<= 1) {
      #pragma unroll
      for (int kk = pp2; kk >= 1; kk >>= 1) {
        #pragma unroll
        for (int j = kk % pp2; j <= 31 - kk; j += 2 * kk) {
          #pragma unroll
          for (int q = 0; q <= ((kk - 1 < 31 - j - kk) ? kk - 1 : 31 - j - kk); q++) {
            if ((q + j) / (2 * pp2) == (q + j + kk) / (2 * pp2)) {
              const int a = q + j, b = q + j + kk;
              if (b < 24) {
                const bool sw = s[b] < s[a];
                const uint32_t lo = min(s[a], s[b]);
                const uint32_t hi = max(s[a], s[b]);
                s[a] = lo; s[b] = hi;
                cswapf(sw, fvx[a], fvx[b]);
                cswapf(sw, fvy[a], fvy[b]);
              }
            }
          }
        }
      }
    }

    // --- replace invalid (keys >= 0xFFFFFFE0 sort last) with sorted[0] ---
    const float v0x = fvx[0], v0y = fvy[0];
    #pragma unroll
    for (int k = 1; k < 24; k++) {
      const bool inv = s[k] >= 0xFFFFFFE0u;
      fvx[k] = inv ? v0x : fvx[k];
      fvy[k] = inv ? v0y : fvy[k];
    }

    // --- shoelace: fp32 coords, fp64 fma accumulation (cyclic) ---
    double cr = 0.0;
    #pragma unroll
    for (int k = 0; k < 24; k++) {
      const int kn = (k + 1) % 24;
      cr = fma((double)fvx[k], (double)fvy[kn], cr);
      cr = fma(-(double)fvy[k], (double)fvx[kn], cr);
    }

    const double inter = fabs(cr) * 0.5;
    const double uni = pw * ph + tw * th - inter;
    float iou = (float)inter / (float)uni;
    iou = fminf(fmaxf(iou, 0.0f), 1.0f);
    iou = fmaxf(iou, 1e-6f);
    loss = -logf(iou);
  }

  // --- block reduction (fp32) + one scaled atomic per block ---
  #pragma unroll
  for (int off = 32; off > 0; off >>= 1)
    loss += __shfl_down(loss, off, 64);
  const int lane = threadIdx.x & 63, wid = threadIdx.x >> 6;
  if (lane == 0) smem[wid] = loss;
  __syncthreads();
  if (threadIdx.x == 0)
    atomicAdd(out, (smem[0] + smem[1] + smem[2] + smem[3]) * invN);
}

extern "C" void kernel_launch(void* const* d_in, const int* in_sizes, int n_in,
                              void* d_out, int out_size, void* d_ws, size_t ws_size,
                              hipStream_t stream) {
  const float* pred = (const float*)d_in[0];
  const float* tgt  = (const float*)d_in[1];
  float* out = (float*)d_out;
  const int N = in_sizes[0] / 5;
  const int nb = (N + 255) / 256;

  hipMemsetAsync(out, 0, sizeof(float), stream);
  riou_loss_kernel<<<nb, 256, 0, stream>>>(pred, tgt, out, N, (float)(1.0 / (double)N));
}

// Round 8
// 98.048 us; speedup vs baseline: 1.7864x; 1.7864x over previous
//
#include <hip/hip_runtime.h>
#include <math.h>
#include <stdint.h>

// Rotated IoU loss, mixed fp64/fp32.
// fp64 spine: corners (poly sincos), intersection num/den (cancellation-critical),
//             shoelace accumulation (fp64 fma of fp32 products).
// fp32: in-box tests, masks (compares of fp64-computed values), vertex coords,
//       masked mean, pseudo-angle keys, iou + log.
// Sort: packed u32 key (27-bit sortable-float pseudo-angle + 5-bit index; stable
//       ties like np.argsort) with fp32 (x,y) payload carried in registers.
// launch_bounds(256,2): rounds 6/7 showed the allocator DEMOTES the sort arrays
// to scratch at caps 128 and ~170 (VGPR_Count 60/56 + ~52MB scratch writes).
// Cap 256 (round 3's config) is the known spill-free regime; this kernel is
// fp32/ILP-rich so 2 waves/SIMD should issue far better than round 3's 37%.

__device__ __forceinline__ float rcp_nr(float x) {
  float r = __builtin_amdgcn_rcpf(x);
  return r * (2.0f - x * r);   // 1 Newton step: ~1 ulp
}

__device__ __forceinline__ void cswapf(bool sw, float& a, float& b) {
  const float t = a; a = sw ? b : a; b = sw ? t : b;
}

// |x| <= ~1.88 guaranteed (pred angle in (-pi/2,pi/2), target += +-0.3).
// Taylor to x^21 / x^22: remainder < 1e-16 relative at |x|=1.88.
__device__ __forceinline__ void sincos_poly(double x, double& s, double& c) {
  const double z = x * x;
  double ps = 1.0 / 51090942171709440000.0;          // 1/21!
  ps = fma(ps, z, -1.0 / 121645100408832000.0);      // -1/19!
  ps = fma(ps, z,  1.0 / 355687428096000.0);
  ps = fma(ps, z, -1.0 / 1307674368000.0);
  ps = fma(ps, z,  1.0 / 6227020800.0);
  ps = fma(ps, z, -1.0 / 39916800.0);
  ps = fma(ps, z,  1.0 / 362880.0);
  ps = fma(ps, z, -1.0 / 5040.0);
  ps = fma(ps, z,  1.0 / 120.0);
  ps = fma(ps, z, -1.0 / 6.0);
  ps = fma(ps, z,  1.0);
  s = x * ps;
  double pc = -1.0 / 1124000727777607680000.0;       // -1/22!
  pc = fma(pc, z,  1.0 / 2432902008176640000.0);     // 1/20!
  pc = fma(pc, z, -1.0 / 6402373705728000.0);
  pc = fma(pc, z,  1.0 / 20922789888000.0);
  pc = fma(pc, z, -1.0 / 87178291200.0);
  pc = fma(pc, z,  1.0 / 479001600.0);
  pc = fma(pc, z, -1.0 / 3628800.0);
  pc = fma(pc, z,  1.0 / 40320.0);
  pc = fma(pc, z, -1.0 / 720.0);
  pc = fma(pc, z,  1.0 / 24.0);
  pc = fma(pc, z, -0.5);
  pc = fma(pc, z,  1.0);
  c = pc;
}

__global__ __launch_bounds__(256, 2) void riou_loss_kernel(
    const float* __restrict__ pred, const float* __restrict__ tgt,
    float* __restrict__ out, int N, float invN)
{
  __shared__ float smem[4];

  const int i = blockIdx.x * 256 + threadIdx.x;
  float loss = 0.0f;
  if (i < N) {
    const float* p = pred + (size_t)i * 5;
    const float* t = tgt + (size_t)i * 5;
    const double px = (double)p[0], py = (double)p[1], pw = (double)p[2],
                 ph = (double)p[3], pa = (double)p[4];
    const double tx = (double)t[0], ty = (double)t[1], tw = (double)t[2],
                 th = (double)t[3], ta = (double)t[4];

    // --- fp64 corners via center +- rotated half-diagonal offsets ---
    double c1x[4], c1y[4], c2x[4], c2y[4];
    {
      double sa, ca; sincos_poly(pa, sa, ca);
      const double hx = 0.5 * pw, hy = 0.5 * ph;
      const double o0x = hx * ca - hy * sa, o0y = hx * sa + hy * ca;   // (+,+)
      const double o1x = -hx * ca - hy * sa, o1y = -hx * sa + hy * ca; // (-,+)
      c1x[0] = px + o0x; c1y[0] = py + o0y;
      c1x[1] = px + o1x; c1y[1] = py + o1y;
      c1x[2] = px - o0x; c1y[2] = py - o0y;
      c1x[3] = px - o1x; c1y[3] = py - o1y;
    }
    {
      double sa, ca; sincos_poly(ta, sa, ca);
      const double hx = 0.5 * tw, hy = 0.5 * th;
      const double o0x = hx * ca - hy * sa, o0y = hx * sa + hy * ca;
      const double o1x = -hx * ca - hy * sa, o1y = -hx * sa + hy * ca;
      c2x[0] = tx + o0x; c2y[0] = ty + o0y;
      c2x[1] = tx + o1x; c2y[1] = ty + o1y;
      c2x[2] = tx - o0x; c2y[2] = ty - o0y;
      c2x[3] = tx - o1x; c2y[3] = ty - o1y;
    }

    // fp32 vertex bank (static-indexed registers): 0..3 c1, 4..7 c2, 8..23 inters
    float fvx[24], fvy[24];
    #pragma unroll
    for (int k = 0; k < 4; k++) {
      fvx[k] = (float)c1x[k]; fvy[k] = (float)c1y[k];
      fvx[4 + k] = (float)c2x[k]; fvy[4 + k] = (float)c2y[k];
    }

    uint32_t vbit = 0;                       // valid-vertex bitmask
    float sxm = 0.0f, sym = 0.0f, nvf = 0.0f;

    // --- in-box tests (fp32; tolerance 1e-6 >> fp32 test error ~1e-7) ---
    {  // c1 corners inside c2
      const float ax = fvx[4], ay = fvy[4];
      const float abx = fvx[5] - ax, aby = fvy[5] - ay;
      const float adx = fvx[7] - ax, ady = fvy[7] - ay;
      const float idab = rcp_nr(abx * abx + aby * aby);
      const float idad = rcp_nr(adx * adx + ady * ady);
      #pragma unroll
      for (int k = 0; k < 4; k++) {
        const float amx = fvx[k] - ax, amy = fvy[k] - ay;
        const float pab = (abx * amx + aby * amy) * idab;
        const float pad = (adx * amx + ady * amy) * idad;
        const bool in2 = (pab > -1e-6f) && (pab < 1.0f + 1e-6f) &&
                         (pad > -1e-6f) && (pad < 1.0f + 1e-6f);
        vbit |= in2 ? (1u << k) : 0u;
        sxm += in2 ? fvx[k] : 0.0f;
        sym += in2 ? fvy[k] : 0.0f;
        nvf += in2 ? 1.0f : 0.0f;
      }
    }
    {  // c2 corners inside c1
      const float ax = fvx[0], ay = fvy[0];
      const float abx = fvx[1] - ax, aby = fvy[1] - ay;
      const float adx = fvx[3] - ax, ady = fvy[3] - ay;
      const float idab = rcp_nr(abx * abx + aby * aby);
      const float idad = rcp_nr(adx * adx + ady * ady);
      #pragma unroll
      for (int k = 0; k < 4; k++) {
        const float amx = fvx[4 + k] - ax, amy = fvy[4 + k] - ay;
        const float pab = (abx * amx + aby * amy) * idab;
        const float pad = (adx * amx + ady * amy) * idad;
        const bool in1 = (pab > -1e-6f) && (pab < 1.0f + 1e-6f) &&
                         (pad > -1e-6f) && (pad < 1.0f + 1e-6f);
        vbit |= in1 ? (1u << (4 + k)) : 0u;
        sxm += in1 ? fvx[4 + k] : 0.0f;
        sym += in1 ? fvy[4 + k] : 0.0f;
        nvf += in1 ? 1.0f : 0.0f;
      }
    }

    // --- edge-edge intersections: fp64 num/den, fp32 masks + points ---
    // e[k+2] = -e[k] (rectangle), so num(a,b) = cross(e2[b], e1[a]) has 4
    // distinct values up to sign: num(a,b) = (-1)^((a>>1)+(b>>1)) * nb[a&1][b&1].
    double e1x[2], e1y[2], e2x[2], e2y[2];
    float f1x[4], f1y[4];
    #pragma unroll
    for (int k = 0; k < 2; k++) {
      e1x[k] = c1x[k + 1] - c1x[k]; e1y[k] = c1y[k + 1] - c1y[k];
      e2x[k] = c2x[k + 1] - c2x[k]; e2y[k] = c2y[k + 1] - c2y[k];
      f1x[k] = (float)e1x[k]; f1y[k] = (float)e1y[k];
      f1x[k + 2] = -f1x[k];   f1y[k + 2] = -f1y[k];
    }
    double nb[2][2];
    #pragma unroll
    for (int a = 0; a < 2; a++)
      #pragma unroll
      for (int b = 0; b < 2; b++)
        nb[a][b] = e2y[b] * e1x[a] - e2x[b] * e1y[a];

    #pragma unroll
    for (int a = 0; a < 4; a++) {
      const double ex1 = (a < 2) ? e1x[a & 1] : -e1x[a & 1];
      const double ey1 = (a < 2) ? e1y[a & 1] : -e1y[a & 1];
      #pragma unroll
      for (int b = 0; b < 4; b++) {
        const double ex2 = (b < 2) ? e2x[b & 1] : -e2x[b & 1];
        const double ey2 = (b < 2) ? e2y[b & 1] : -e2y[b & 1];
        const double dx13 = c1x[a] - c2x[b], dy13 = c1y[a] - c2y[b];
        const double num  = (((a >> 1) ^ (b >> 1)) & 1) ? -nb[a & 1][b & 1]
                                                        :  nb[a & 1][b & 1];
        const double dent = ex2 * dy13 - ey2 * dx13;
        const double denu = ex1 * dy13 - ey1 * dx13;
        const float numf = (float)num, dtf = (float)dent, duf = (float)denu;
        // t,u strictly in (0,1): sign tests, no division
        const bool mk = (numf > 0.0f)
            ? ((dtf > 0.0f) && (dtf < numf) && (duf > 0.0f) && (duf < numf))
            : ((numf < 0.0f) && (dtf < 0.0f) && (dtf > numf) && (duf < 0.0f) && (duf > numf));
        // ref quirk: t = den_t / (num + 1e-8)
        const float tt = dtf * rcp_nr(numf + 1e-8f);
        const float ix = fvx[a] + tt * f1x[a];
        const float iy = fvy[a] + tt * f1y[a];
        const int id = 8 + a * 4 + b;
        fvx[id] = ix; fvy[id] = iy;
        vbit |= mk ? (1u << id) : 0u;
        sxm += mk ? ix : 0.0f;
        sym += mk ? iy : 0.0f;
        nvf += mk ? 1.0f : 0.0f;
      }
    }

    // --- masked mean + packed sort keys ---
    const float invn = 1.0f / fmaxf(nvf, 1.0f);
    const float mx = sxm * invn, my = sym * invn;
    uint32_t s[24];
    #pragma unroll
    for (int k = 0; k < 24; k++) {
      const float xf = fvx[k] - mx, yf = fvy[k] - my;
      const float den = fabsf(xf) + fabsf(yf);
      const float pp = (den == 0.0f) ? 1.0f : xf * __builtin_amdgcn_rcpf(den);
      const float ky = (yf >= 0.0f) ? -pp : (pp - 2.0f);  // monotone in atan2 over (-pi,pi]
      const uint32_t u = __float_as_uint(ky);
      const uint32_t srt = u ^ ((u & 0x80000000u) ? 0xFFFFFFFFu : 0x80000000u);
      const bool valid = (vbit >> k) & 1u;
      // 27-bit key + 5-bit index (stable ties, like np.argsort); invalid -> max class
      s[k] = valid ? ((srt & 0xFFFFFFE0u) | (uint32_t)k) : (0xFFFFFFE0u | (uint32_t)k);
    }

    // --- Batcher odd-even mergesort, n=32 pruned to 24 wires, payload in regs ---
    #pragma unroll
    for (int pp2 = 1; pp2 < 32; pp2 <<= 1) {
      #pragma unroll
      for (int kk = pp2; kk >= 1; kk >>= 1) {
        #pragma unroll
        for (int j = kk % pp2; j <= 31 - kk; j += 2 * kk) {
          #pragma unroll
          for (int q = 0; q <= ((kk - 1 < 31 - j - kk) ? kk - 1 : 31 - j - kk); q++) {
            if ((q + j) / (2 * pp2) == (q + j + kk) / (2 * pp2)) {
              const int a = q + j, b = q + j + kk;
              if (b < 24) {
                const bool sw = s[b] < s[a];
                const uint32_t lo = min(s[a], s[b]);
                const uint32_t hi = max(s[a], s[b]);
                s[a] = lo; s[b] = hi;
                cswapf(sw, fvx[a], fvx[b]);
                cswapf(sw, fvy[a], fvy[b]);
              }
            }
          }
        }
      }
    }

    // --- replace invalid (keys >= 0xFFFFFFE0 sort last) with sorted[0] ---
    const float v0x = fvx[0], v0y = fvy[0];
    #pragma unroll
    for (int k = 1; k < 24; k++) {
      const bool inv = s[k] >= 0xFFFFFFE0u;
      fvx[k] = inv ? v0x : fvx[k];
      fvy[k] = inv ? v0y : fvy[k];
    }

    // --- shoelace: fp32 coords, fp64 fma accumulation (cyclic) ---
    double cr = 0.0;
    #pragma unroll
    for (int k = 0; k < 24; k++) {
      const int kn = (k + 1) % 24;
      cr = fma((double)fvx[k], (double)fvy[kn], cr);
      cr = fma(-(double)fvy[k], (double)fvx[kn], cr);
    }

    const double inter = fabs(cr) * 0.5;
    const double uni = pw * ph + tw * th - inter;
    float iou = (float)inter / (float)uni;
    iou = fminf(fmaxf(iou, 0.0f), 1.0f);
    iou = fmaxf(iou, 1e-6f);
    loss = -logf(iou);
  }

  // --- block reduction (fp32) + one scaled atomic per block ---
  #pragma unroll
  for (int off = 32; off > 0; off >>= 1)
    loss += __shfl_down(loss, off, 64);
  const int lane = threadIdx.x & 63, wid = threadIdx.x >> 6;
  if (lane == 0) smem[wid] = loss;
  __syncthreads();
  if (threadIdx.x == 0)
    atomicAdd(out, (smem[0] + smem[1] + smem[2] + smem[3]) * invN);
}

extern "C" void kernel_launch(void* const* d_in, const int* in_sizes, int n_in,
                              void* d_out, int out_size, void* d_ws, size_t ws_size,
                              hipStream_t stream) {
  const float* pred = (const float*)d_in[0];
  const float* tgt  = (const float*)d_in[1];
  float* out = (float*)d_out;
  const int N = in_sizes[0] / 5;
  const int nb = (N + 255) / 256;

  hipMemsetAsync(out, 0, sizeof(float), stream);
  riou_loss_kernel<<<nb, 256, 0, stream>>>(pred, tgt, out, N, (float)(1.0 / (double)N));
}

// Round 9
// 92.612 us; speedup vs baseline: 1.8913x; 1.0587x over previous
//
#include <hip/hip_runtime.h>
#include <math.h>
#include <stdint.h>

// Rotated IoU loss via Green's theorem:
//   2*Area(A inter B) = sum over directed boundary pieces of (x1*y2 - x2*y1),
// where the pieces are each edge of A clipped to B plus each edge of B clipped
// to A (Liang-Barsky slab clipping against the rectangle's two axes).
// Replaces the reference's vertex-set + angle-sort machinery entirely; equal
// up to measure-zero coincident-boundary configs and fp32 clip noise (~1e-3
// absolute area -> ~1e-4 mean-loss error vs the 1.96e-2 threshold).
// fp64: corner construction (poly sincos, anchors geometry to the fp64 ref)
//       and the cross-product accumulation (fp32 products are exact in fp64).
// fp32: everything else. No sort, no LDS tiles, ~70-90 VGPR, no launch bounds.

// |x| <= ~1.88 (pred angle in (-pi/2,pi/2), target +- 0.3).
// sin to x^13 (rem ~1e-8 rel), cos to x^14 (rem ~1e-9).
__device__ __forceinline__ void sincos13(double x, double& s, double& c) {
  const double z = x * x;
  double ps = 1.0 / 6227020800.0;            // 1/13!
  ps = fma(ps, z, -1.0 / 39916800.0);        // -1/11!
  ps = fma(ps, z,  1.0 / 362880.0);          // 1/9!
  ps = fma(ps, z, -1.0 / 5040.0);            // -1/7!
  ps = fma(ps, z,  1.0 / 120.0);             // 1/5!
  ps = fma(ps, z, -1.0 / 6.0);               // -1/3!
  ps = fma(ps, z,  1.0);
  s = x * ps;
  double pc = -1.0 / 87178291200.0;          // -1/14!
  pc = fma(pc, z,  1.0 / 479001600.0);       // 1/12!
  pc = fma(pc, z, -1.0 / 3628800.0);         // -1/10!
  pc = fma(pc, z,  1.0 / 40320.0);           // 1/8!
  pc = fma(pc, z, -1.0 / 720.0);             // -1/6!
  pc = fma(pc, z,  1.0 / 24.0);              // 1/4!
  pc = fma(pc, z, -0.5);
  pc = fma(pc, z,  1.0);
  c = pc;
}

// One slab: s(t) = s0 + t*sd must lie in [0, U]. Emits the t-interval.
__device__ __forceinline__ void clip_axis(float s0, float sd, float U,
                                          float& tl, float& th) {
  const bool para = (sd == 0.0f);
  const float inv = __builtin_amdgcn_rcpf(sd);   // ~1 ulp; t err ~1e-7 rel
  const float a = (0.0f - s0) * inv;
  const float b = (U - s0) * inv;
  const bool inr = (s0 >= 0.0f) && (s0 <= U);
  tl = para ? (inr ? -3e30f : 3e30f) : fminf(a, b);
  th = para ? (inr ? 3e30f : -3e30f) : fmaxf(a, b);
}

// Clip directed segment P + t*D (t in [0,1]) to rectangle {b0, AB, AD} and
// accumulate the Green's-theorem contribution of the clipped piece.
__device__ __forceinline__ void clip_edge(
    float Px, float Py, float Dx, float Dy,
    float b0x, float b0y, float ABx, float ABy,
    float ADx, float ADy, float Uab, float Uad, double& acc)
{
  const float rx = Px - b0x, ry = Py - b0y;
  const float s0a = rx * ABx + ry * ABy;
  const float sda = Dx * ABx + Dy * ABy;
  const float s0d = rx * ADx + ry * ADy;
  const float sdd = Dx * ADx + Dy * ADy;
  float tl1, th1, tl2, th2;
  clip_axis(s0a, sda, Uab, tl1, th1);
  clip_axis(s0d, sdd, Uad, tl2, th2);
  float tlo = fmaxf(fmaxf(tl1, tl2), 0.0f);      // v_max3
  float thi = fminf(fminf(th1, th2), 1.0f);      // v_min3
  const bool ok = thi > tlo;
  tlo = ok ? tlo : 0.0f;                         // empty -> degenerate point:
  thi = ok ? thi : 0.0f;                         // exact 0 contribution below
  const float x1 = fmaf(tlo, Dx, Px), y1 = fmaf(tlo, Dy, Py);
  const float x2 = fmaf(thi, Dx, Px), y2 = fmaf(thi, Dy, Py);
  // fp32*fp32 products are exact in fp64 fma; empty piece cancels exactly.
  acc = fma((double)x1, (double)y2, acc);
  acc = fma(-(double)x2, (double)y1, acc);
}

__global__ void riou_loss_kernel(
    const float* __restrict__ pred, const float* __restrict__ tgt,
    float* __restrict__ out, int N, float invN)
{
  __shared__ float smem[4];

  const int i = blockIdx.x * 256 + threadIdx.x;
  float loss = 0.0f;
  if (i < N) {
    const float* p = pred + (size_t)i * 5;
    const float* t = tgt + (size_t)i * 5;
    const float pxf = p[0], pyf = p[1], pwf = p[2], phf = p[3], paf = p[4];
    const float txf = t[0], tyf = t[1], twf = t[2], thf = t[3], taf = t[4];

    // --- fp64 corners (center +- rotated half-diagonals), downcast to fp32 ---
    // corner order (ref): (+,+), (-,+), (-,-), (+,-)  -> CCW
    float ax[4], ay[4], bx[4], by[4];
    {
      double sa, ca; sincos13((double)paf, sa, ca);
      const double hx = 0.5 * (double)pwf, hy = 0.5 * (double)phf;
      const double o0x = hx * ca - hy * sa, o0y = hx * sa + hy * ca;   // (+,+)
      const double o1x = -hx * ca - hy * sa, o1y = -hx * sa + hy * ca; // (-,+)
      ax[0] = (float)((double)pxf + o0x); ay[0] = (float)((double)pyf + o0y);
      ax[1] = (float)((double)pxf + o1x); ay[1] = (float)((double)pyf + o1y);
      ax[2] = (float)((double)pxf - o0x); ay[2] = (float)((double)pyf - o0y);
      ax[3] = (float)((double)pxf - o1x); ay[3] = (float)((double)pyf - o1y);
    }
    {
      double sa, ca; sincos13((double)taf, sa, ca);
      const double hx = 0.5 * (double)twf, hy = 0.5 * (double)thf;
      const double o0x = hx * ca - hy * sa, o0y = hx * sa + hy * ca;
      const double o1x = -hx * ca - hy * sa, o1y = -hx * sa + hy * ca;
      bx[0] = (float)((double)txf + o0x); by[0] = (float)((double)tyf + o0y);
      bx[1] = (float)((double)txf + o1x); by[1] = (float)((double)tyf + o1y);
      bx[2] = (float)((double)txf - o0x); by[2] = (float)((double)tyf - o0y);
      bx[3] = (float)((double)txf - o1x); by[3] = (float)((double)tyf - o1y);
    }

    // --- clip-region constants for each rectangle ---
    const float ABxA = ax[1] - ax[0], AByA = ay[1] - ay[0];
    const float ADxA = ax[3] - ax[0], ADyA = ay[3] - ay[0];
    const float UabA = ABxA * ABxA + AByA * AByA;
    const float UadA = ADxA * ADxA + ADyA * ADyA;
    const float ABxB = bx[1] - bx[0], AByB = by[1] - by[0];
    const float ADxB = bx[3] - bx[0], ADyB = by[3] - by[0];
    const float UabB = ABxB * ABxB + AByB * AByB;
    const float UadB = ADxB * ADxB + ADyB * ADyB;

    // --- Green's-theorem boundary integral ---
    double acc = 0.0;
    #pragma unroll
    for (int k = 0; k < 4; k++) {           // edges of A clipped to B
      const int kn = (k + 1) & 3;
      clip_edge(ax[k], ay[k], ax[kn] - ax[k], ay[kn] - ay[k],
                bx[0], by[0], ABxB, AByB, ADxB, ADyB, UabB, UadB, acc);
    }
    #pragma unroll
    for (int k = 0; k < 4; k++) {           // edges of B clipped to A
      const int kn = (k + 1) & 3;
      clip_edge(bx[k], by[k], bx[kn] - bx[k], by[kn] - by[k],
                ax[0], ay[0], ABxA, AByA, ADxA, ADyA, UabA, UadA, acc);
    }

    const double inter = 0.5 * fabs(acc);
    const double uni = (double)pwf * (double)phf
                     + (double)twf * (double)thf - inter;
    float iou = (float)inter / (float)uni;
    iou = fminf(fmaxf(iou, 0.0f), 1.0f);
    iou = fmaxf(iou, 1e-6f);
    loss = -logf(iou);
  }

  // --- block reduction + one scaled atomic per block ---
  #pragma unroll
  for (int off = 32; off > 0; off >>= 1)
    loss += __shfl_down(loss, off, 64);
  const int lane = threadIdx.x & 63, wid = threadIdx.x >> 6;
  if (lane == 0) smem[wid] = loss;
  __syncthreads();
  if (threadIdx.x == 0)
    atomicAdd(out, (smem[0] + smem[1] + smem[2] + smem[3]) * invN);
}

extern "C" void kernel_launch(void* const* d_in, const int* in_sizes, int n_in,
                              void* d_out, int out_size, void* d_ws, size_t ws_size,
                              hipStream_t stream) {
  const float* pred = (const float*)d_in[0];
  const float* tgt  = (const float*)d_in[1];
  float* out = (float*)d_out;
  const int N = in_sizes[0] / 5;
  const int nb = (N + 255) / 256;

  hipMemsetAsync(out, 0, sizeof(float), stream);
  riou_loss_kernel<<<nb, 256, 0, stream>>>(pred, tgt, out, N, (float)(1.0 / (double)N));
}

// Round 10
// 82.261 us; speedup vs baseline: 2.1293x; 1.1258x over previous
//
#include <hip/hip_runtime.h>
#include <math.h>
#include <stdint.h>

// Rotated IoU loss via Green's theorem (all-fp32 geometry):
//   2*Area(A inter B) = sum over directed boundary pieces of (x1*y2 - x2*y1),
// pieces = each edge of A clipped to B + each edge of B clipped to A
// (Liang-Barsky slab clipping). No vertex set, no masks, no sort — and no
// decision thresholds, so fp32 errors degrade the area smoothly (no
// misclassification cliffs). fp64 kept ONLY for the 16-term cross-product
// accumulation (fp32 products exact in fp64 fma; cancellation-heavy).
// Round 9 (fp64 corners) scored absmax 0.0 vs the 1.96e-2 threshold; the
// fp32-corner mean-loss shift is est. <= ~2e-3 — 10x margin retained.
// Grid-stride: 1024 blocks x 256 thr, ~2 elems/thread, 1024 total atomics.

// One slab: s(t) = s0 + t*sd must lie in [0, U]. Emits the t-interval.
// Near-parallel (tiny sd): a,b same-sign-huge when outside -> empty after
// [0,1] clamp; spanning when inside -> full interval. Exact sd==0 via para.
__device__ __forceinline__ void clip_axis(float s0, float sd, float U,
                                          float& tl, float& th) {
  const bool para = (sd == 0.0f);
  const float inv = __builtin_amdgcn_rcpf(sd);   // ~1 ulp
  const float a = (0.0f - s0) * inv;
  const float b = (U - s0) * inv;
  const bool inr = (s0 >= 0.0f) && (s0 <= U);
  tl = para ? (inr ? -3e30f : 3e30f) : fminf(a, b);
  th = para ? (inr ? 3e30f : -3e30f) : fmaxf(a, b);
}

// Clip directed segment P + t*D (t in [0,1]) to rectangle {b0, AB, AD} and
// accumulate the Green's-theorem contribution of the clipped piece.
__device__ __forceinline__ void clip_edge(
    float Px, float Py, float Dx, float Dy,
    float b0x, float b0y, float ABx, float ABy,
    float ADx, float ADy, float Uab, float Uad, double& acc)
{
  const float rx = Px - b0x, ry = Py - b0y;
  const float s0a = rx * ABx + ry * ABy;
  const float sda = Dx * ABx + Dy * ABy;
  const float s0d = rx * ADx + ry * ADy;
  const float sdd = Dx * ADx + Dy * ADy;
  float tl1, th1, tl2, th2;
  clip_axis(s0a, sda, Uab, tl1, th1);
  clip_axis(s0d, sdd, Uad, tl2, th2);
  float tlo = fmaxf(fmaxf(tl1, tl2), 0.0f);      // v_max3
  float thi = fminf(fminf(th1, th2), 1.0f);      // v_min3
  const bool ok = thi > tlo;
  tlo = ok ? tlo : 0.0f;                         // empty -> degenerate point:
  thi = ok ? thi : 0.0f;                         // exact 0 contribution below
  const float x1 = fmaf(tlo, Dx, Px), y1 = fmaf(tlo, Dy, Py);
  const float x2 = fmaf(thi, Dx, Px), y2 = fmaf(thi, Dy, Py);
  acc = fma((double)x1, (double)y2, acc);
  acc = fma(-(double)x2, (double)y1, acc);
}

__global__ void riou_loss_kernel(
    const float* __restrict__ pred, const float* __restrict__ tgt,
    float* __restrict__ out, int N, float invN)
{
  __shared__ float smem[4];

  float loss = 0.0f;
  const int stride = (int)gridDim.x * 256;
  for (int i = (int)blockIdx.x * 256 + (int)threadIdx.x; i < N; i += stride) {
    const float* p = pred + (size_t)i * 5;
    const float* t = tgt + (size_t)i * 5;
    const float pxf = p[0], pyf = p[1], pwf = p[2], phf = p[3], paf = p[4];
    const float txf = t[0], tyf = t[1], twf = t[2], thf = t[3], taf = t[4];

    // --- fp32 corners (center +- rotated half-diagonals), HW sincos ---
    // corner order (ref): (+,+), (-,+), (-,-), (+,-)  -> CCW
    float ax[4], ay[4], bx[4], by[4];
    {
      float sa, ca; __sincosf(paf, &sa, &ca);
      const float hx = 0.5f * pwf, hy = 0.5f * phf;
      const float o0x = hx * ca - hy * sa, o0y = hx * sa + hy * ca;   // (+,+)
      const float o1x = -hx * ca - hy * sa, o1y = -hx * sa + hy * ca; // (-,+)
      ax[0] = pxf + o0x; ay[0] = pyf + o0y;
      ax[1] = pxf + o1x; ay[1] = pyf + o1y;
      ax[2] = pxf - o0x; ay[2] = pyf - o0y;
      ax[3] = pxf - o1x; ay[3] = pyf - o1y;
    }
    {
      float sa, ca; __sincosf(taf, &sa, &ca);
      const float hx = 0.5f * twf, hy = 0.5f * thf;
      const float o0x = hx * ca - hy * sa, o0y = hx * sa + hy * ca;
      const float o1x = -hx * ca - hy * sa, o1y = -hx * sa + hy * ca;
      bx[0] = txf + o0x; by[0] = tyf + o0y;
      bx[1] = txf + o1x; by[1] = tyf + o1y;
      bx[2] = txf - o0x; by[2] = tyf - o0y;
      bx[3] = txf - o1x; by[3] = tyf - o1y;
    }

    // --- clip-region constants for each rectangle ---
    const float ABxA = ax[1] - ax[0], AByA = ay[1] - ay[0];
    const float ADxA = ax[3] - ax[0], ADyA = ay[3] - ay[0];
    const float UabA = ABxA * ABxA + AByA * AByA;
    const float UadA = ADxA * ADxA + ADyA * ADyA;
    const float ABxB = bx[1] - bx[0], AByB = by[1] - by[0];
    const float ADxB = bx[3] - bx[0], ADyB = by[3] - by[0];
    const float UabB = ABxB * ABxB + AByB * AByB;
    const float UadB = ADxB * ADxB + ADyB * ADyB;

    // --- Green's-theorem boundary integral ---
    double acc = 0.0;
    #pragma unroll
    for (int k = 0; k < 4; k++) {           // edges of A clipped to B
      const int kn = (k + 1) & 3;
      clip_edge(ax[k], ay[k], ax[kn] - ax[k], ay[kn] - ay[k],
                bx[0], by[0], ABxB, AByB, ADxB, ADyB, UabB, UadB, acc);
    }
    #pragma unroll
    for (int k = 0; k < 4; k++) {           // edges of B clipped to A
      const int kn = (k + 1) & 3;
      clip_edge(bx[k], by[k], bx[kn] - bx[k], by[kn] - by[k],
                ax[0], ay[0], ABxA, AByA, ADxA, ADyA, UabA, UadA, acc);
    }

    const float inter = 0.5f * fabsf((float)acc);
    const float uni = pwf * phf + twf * thf - inter;
    float iou = inter * __builtin_amdgcn_rcpf(uni);
    iou = fminf(fmaxf(iou, 0.0f), 1.0f);
    iou = fmaxf(iou, 1e-6f);
    loss += -logf(iou);
  }

  // --- block reduction + one scaled atomic per block ---
  #pragma unroll
  for (int off = 32; off > 0; off >>= 1)
    loss += __shfl_down(loss, off, 64);
  const int lane = threadIdx.x & 63, wid = threadIdx.x >> 6;
  if (lane == 0) smem[wid] = loss;
  __syncthreads();
  if (threadIdx.x == 0)
    atomicAdd(out, (smem[0] + smem[1] + smem[2] + smem[3]) * invN);
}

extern "C" void kernel_launch(void* const* d_in, const int* in_sizes, int n_in,
                              void* d_out, int out_size, void* d_ws, size_t ws_size,
                              hipStream_t stream) {
  const float* pred = (const float*)d_in[0];
  const float* tgt  = (const float*)d_in[1];
  float* out = (float*)d_out;
  const int N = in_sizes[0] / 5;
  int nb = (N + 255) / 256;
  if (nb > 1024) nb = 1024;                 // 4 blocks/CU; grid-stride the rest

  hipMemsetAsync(out, 0, sizeof(float), stream);
  riou_loss_kernel<<<nb, 256, 0, stream>>>(pred, tgt, out, N, (float)(1.0 / (double)N));
}

// Round 11
// 81.215 us; speedup vs baseline: 2.1567x; 1.0129x over previous
//
#include <hip/hip_runtime.h>
#include <math.h>
#include <stdint.h>

// Rotated IoU loss via Green's theorem, all-fp32:
//   2*Area(A inter B) = sum over directed boundary pieces of cross(P1,P2),
// pieces = edges of A clipped to B + edges of B clipped to A (Liang-Barsky).
// KEY IDENTITY (exact, bilinear): for P1 = P + tlo*D, P2 = P + thi*D,
//   cross(P1,P2) = (thi - tlo) * cross(P,D),  and cross(P,D) = cross(Ck,Ck+1).
// So no clipped endpoints are ever materialized: per edge just dt * crossPD.
// Empty interval: dt = max(thi - tlo, 0) = 0 exactly. No decision thresholds
// anywhere -> fp32 noise degrades area smoothly (no misclassification cliffs).
// fp32 acc: 16 terms <=2e4 cancelling to ~2*inter; err ~5e-3 abs -> ~1e-5 on
// the mean loss vs 1.96e-2 threshold (round 10 scored absmax 0.0).

__device__ __forceinline__ void clip_axis(float s0, float sd, float U,
                                          float& tl, float& th) {
  const bool para = (sd == 0.0f);
  const float inv = __builtin_amdgcn_rcpf(sd);   // ~1 ulp
  const float a = (0.0f - s0) * inv;
  const float b = (U - s0) * inv;
  const bool inr = (s0 >= 0.0f) && (s0 <= U);
  tl = para ? (inr ? -3e30f : 3e30f) : fminf(a, b);
  th = para ? (inr ? 3e30f : -3e30f) : fmaxf(a, b);
}

// Clip segment P + t*D (t in [0,1]) against rectangle {b0, AB, AD}; add
// (thi - tlo) * crossPD to acc (crossPD = cross of the edge's corner pair).
__device__ __forceinline__ void clip_edge(
    float Px, float Py, float Dx, float Dy, float crossPD,
    float b0x, float b0y, float ABx, float ABy,
    float ADx, float ADy, float Uab, float Uad, float& acc)
{
  const float rx = Px - b0x, ry = Py - b0y;
  const float s0a = rx * ABx + ry * ABy;
  const float sda = Dx * ABx + Dy * ABy;
  const float s0d = rx * ADx + ry * ADy;
  const float sdd = Dx * ADx + Dy * ADy;
  float tl1, th1, tl2, th2;
  clip_axis(s0a, sda, Uab, tl1, th1);
  clip_axis(s0d, sdd, Uad, tl2, th2);
  const float tlo = fmaxf(fmaxf(tl1, tl2), 0.0f);   // v_max3
  const float thi = fminf(fminf(th1, th2), 1.0f);   // v_min3
  const float dt = fmaxf(thi - tlo, 0.0f);          // empty -> exactly 0
  acc = fmaf(dt, crossPD, acc);
}

__global__ void riou_loss_kernel(
    const float* __restrict__ pred, const float* __restrict__ tgt,
    float* __restrict__ out, int N, float invN)
{
  __shared__ float smem[4];

  float loss = 0.0f;
  const int stride = (int)gridDim.x * 256;
  for (int i = (int)blockIdx.x * 256 + (int)threadIdx.x; i < N; i += stride) {
    const float* p = pred + (size_t)i * 5;
    const float* t = tgt + (size_t)i * 5;
    const float pxf = p[0], pyf = p[1], pwf = p[2], phf = p[3], paf = p[4];
    const float txf = t[0], tyf = t[1], twf = t[2], thf = t[3], taf = t[4];

    // --- fp32 corners (center +- rotated half-diagonals), HW sincos ---
    // corner order (ref): (+,+), (-,+), (-,-), (+,-)
    float ax[4], ay[4], bx[4], by[4];
    {
      float sa, ca; __sincosf(paf, &sa, &ca);
      const float hx = 0.5f * pwf, hy = 0.5f * phf;
      const float o0x = hx * ca - hy * sa, o0y = hx * sa + hy * ca;   // (+,+)
      const float o1x = -hx * ca - hy * sa, o1y = -hx * sa + hy * ca; // (-,+)
      ax[0] = pxf + o0x; ay[0] = pyf + o0y;
      ax[1] = pxf + o1x; ay[1] = pyf + o1y;
      ax[2] = pxf - o0x; ay[2] = pyf - o0y;
      ax[3] = pxf - o1x; ay[3] = pyf - o1y;
    }
    {
      float sa, ca; __sincosf(taf, &sa, &ca);
      const float hx = 0.5f * twf, hy = 0.5f * thf;
      const float o0x = hx * ca - hy * sa, o0y = hx * sa + hy * ca;
      const float o1x = -hx * ca - hy * sa, o1y = -hx * sa + hy * ca;
      bx[0] = txf + o0x; by[0] = tyf + o0y;
      bx[1] = txf + o1x; by[1] = tyf + o1y;
      bx[2] = txf - o0x; by[2] = tyf - o0y;
      bx[3] = txf - o1x; by[3] = tyf - o1y;
    }

    // --- clip-region constants for each rectangle ---
    const float ABxA = ax[1] - ax[0], AByA = ay[1] - ay[0];
    const float ADxA = ax[3] - ax[0], ADyA = ay[3] - ay[0];
    const float UabA = ABxA * ABxA + AByA * AByA;
    const float UadA = ADxA * ADxA + ADyA * ADyA;
    const float ABxB = bx[1] - bx[0], AByB = by[1] - by[0];
    const float ADxB = bx[3] - bx[0], ADyB = by[3] - by[0];
    const float UabB = ABxB * ABxB + AByB * AByB;
    const float UadB = ADxB * ADxB + ADyB * ADyB;

    // --- Green's-theorem boundary integral via dt * cross(Ck, Ck+1) ---
    float acc = 0.0f;
    #pragma unroll
    for (int k = 0; k < 4; k++) {           // edges of A clipped to B
      const int kn = (k + 1) & 3;
      const float crossPD = ax[k] * ay[kn] - ax[kn] * ay[k];
      clip_edge(ax[k], ay[k], ax[kn] - ax[k], ay[kn] - ay[k], crossPD,
                bx[0], by[0], ABxB, AByB, ADxB, ADyB, UabB, UadB, acc);
    }
    #pragma unroll
    for (int k = 0; k < 4; k++) {           // edges of B clipped to A
      const int kn = (k + 1) & 3;
      const float crossPD = bx[k] * by[kn] - bx[kn] * by[k];
      clip_edge(bx[k], by[k], bx[kn] - bx[k], by[kn] - by[k], crossPD,
                ax[0], ay[0], ABxA, AByA, ADxA, ADyA, UabA, UadA, acc);
    }

    const float inter = 0.5f * fabsf(acc);
    const float uni = pwf * phf + twf * thf - inter;
    float iou = inter * __builtin_amdgcn_rcpf(uni);
    iou = fminf(fmaxf(iou, 0.0f), 1.0f);
    iou = fmaxf(iou, 1e-6f);
    loss += -logf(iou);
  }

  // --- block reduction + one scaled atomic per block ---
  #pragma unroll
  for (int off = 32; off > 0; off >>= 1)
    loss += __shfl_down(loss, off, 64);
  const int lane = threadIdx.x & 63, wid = threadIdx.x >> 6;
  if (lane == 0) smem[wid] = loss;
  __syncthreads();
  if (threadIdx.x == 0)
    atomicAdd(out, (smem[0] + smem[1] + smem[2] + smem[3]) * invN);
}

extern "C" void kernel_launch(void* const* d_in, const int* in_sizes, int n_in,
                              void* d_out, int out_size, void* d_ws, size_t ws_size,
                              hipStream_t stream) {
  const float* pred = (const float*)d_in[0];
  const float* tgt  = (const float*)d_in[1];
  float* out = (float*)d_out;
  const int N = in_sizes[0] / 5;
  int nb = (N + 255) / 256;
  if (nb > 1024) nb = 1024;                 // 4 blocks/CU; grid-stride the rest

  hipMemsetAsync(out, 0, sizeof(float), stream);
  riou_loss_kernel<<<nb, 256, 0, stream>>>(pred, tgt, out, N, (float)(1.0 / (double)N));
}